// Round 1
// baseline (403.924 us; speedup 1.0000x reference)
//
#include <hip/hip_runtime.h>
#include <hip/hip_bf16.h>

typedef __attribute__((ext_vector_type(8))) short short8;
typedef __attribute__((ext_vector_type(4))) float f32x4;

#define NEDGES 800000
#define BM 64
#define CAT 384
#define APAD 8
#define HPAD 8

__device__ __forceinline__ unsigned short f2bf(float f) {
  union { float f; unsigned u; } v; v.f = f;
  unsigned r = v.u + 0x7fffu + ((v.u >> 16) & 1u);
  return (unsigned short)(r >> 16);
}

// ---------------- prep kernels (tiny, run every launch; deterministic) ----------------

// Wgt[n*384+k] = bf16(gamma[k] * W1[k*128+n]);  W2t[n*128+k] = bf16(W2[k*128+n])
__global__ void prep_w(const float* __restrict__ W1, const float* __restrict__ gamma,
                       const float* __restrict__ W2,
                       unsigned short* __restrict__ Wgt, unsigned short* __restrict__ W2t) {
  int idx = blockIdx.x * 256 + threadIdx.x;
  if (idx < 128 * 384) {
    int n = idx / 384, k = idx % 384;
    Wgt[idx] = f2bf(gamma[k] * W1[k * 128 + n]);
  }
  if (idx < 128 * 128) {
    int n = idx / 128, k = idx % 128;
    W2t[idx] = f2bf(W2[k * 128 + n]);
  }
}

// G[n] = sum_k gamma[k]*W1[k,n];  C1[n] = sum_k beta[k]*W1[k,n] + b1[n]
__global__ void prep_gc(const float* __restrict__ W1, const float* __restrict__ gamma,
                        const float* __restrict__ beta, const float* __restrict__ b1,
                        float* __restrict__ G, float* __restrict__ C1) {
  int n = threadIdx.x;  // 128 threads
  float g = 0.f, b = 0.f;
  for (int k = 0; k < 384; ++k) {
    float w = W1[k * 128 + n];
    g = fmaf(gamma[k], w, g);
    b = fmaf(beta[k], w, b);
  }
  G[n] = g;
  C1[n] = b + b1[n];
}

// ---------------- fused main kernel ----------------
// Per block: 64 edges. Phase1: gather x_i|x_j|e -> bf16 LDS + LN stats.
// GEMM1 (folded LN): h1 = rstd*(cat@Wg - mu*G) + C1, leaky -> bf16 LDS.
// GEMM2: h2 = h1@W2t. out = e + h2 + b2.
__global__ __launch_bounds__(256, 2) void edge_fused(
    const float* __restrict__ node_feat,
    const int* __restrict__ esrc,
    const int* __restrict__ edst,
    const float* __restrict__ eptr,
    const unsigned short* __restrict__ Wgt,
    const unsigned short* __restrict__ W2t,
    const float* __restrict__ Gv,
    const float* __restrict__ C1v,
    const float* __restrict__ b2v,
    float* __restrict__ out) {
  __shared__ unsigned short Abuf[BM][CAT + APAD];   // 64 x 392 bf16 = 50176 B
  __shared__ unsigned short Hbuf[BM][128 + HPAD];   // 64 x 136 bf16 = 17408 B
  __shared__ float muS[BM];
  __shared__ float rsS[BM];

  const int tid = threadIdx.x;
  const int blk = blockIdx.x;

  // ---------- Phase 1: gather + stats + bf16 staging ----------
  {
    const int r = tid >> 2;   // edge row within tile (0..63)
    const int t = tid & 3;    // 4 threads per row (same wave: lanes 4r..4r+3)
    const size_t gid = (size_t)blk * BM + r;
    const int si = esrc[gid];
    const int di = edst[gid];
    const float4* __restrict__ p0 = (const float4*)(node_feat + (size_t)si * 128);
    const float4* __restrict__ p1 = (const float4*)(node_feat + (size_t)di * 128);
    const float4* __restrict__ p2 = (const float4*)(eptr + gid * 128);
    float sum = 0.f, sq = 0.f;
#pragma unroll
    for (int s = 0; s < 3; ++s) {
      const float4* __restrict__ p = (s == 0) ? p0 : (s == 1) ? p1 : p2;
#pragma unroll
      for (int i = 0; i < 8; ++i) {
        float4 v = p[t + 4 * i];
        sum += (v.x + v.y) + (v.z + v.w);
        sq = fmaf(v.x, v.x, sq); sq = fmaf(v.y, v.y, sq);
        sq = fmaf(v.z, v.z, sq); sq = fmaf(v.w, v.w, sq);
        ushort4 pk;
        pk.x = f2bf(v.x); pk.y = f2bf(v.y); pk.z = f2bf(v.z); pk.w = f2bf(v.w);
        *(ushort4*)&Abuf[r][s * 128 + (t + 4 * i) * 4] = pk;
      }
    }
    // 4-lane butterfly: all 4 lanes of the row end with the totals
    sum += __shfl_xor(sum, 1); sum += __shfl_xor(sum, 2);
    sq  += __shfl_xor(sq, 1);  sq  += __shfl_xor(sq, 2);
    const float mu = sum * (1.f / 384.f);
    const float var = fmaf(-mu, mu, sq * (1.f / 384.f));
    const float rstd = rsqrtf(var + 1e-5f);
    if (t == 0) { muS[r] = mu; rsS[r] = rstd; }
  }
  __syncthreads();

  const int l = tid & 63;
  const int w = tid >> 6;        // wave 0..3, owns n-cols [32w, 32w+32)
  const int lr = l & 15;
  const int lkrow = l >> 4;
  const int lk = lkrow * 8;
  const int n0 = w * 32;

  float Gn[2], C1n[2], b2n[2];
#pragma unroll
  for (int nf = 0; nf < 2; ++nf) {
    const int n = n0 + nf * 16 + lr;
    Gn[nf] = Gv[n]; C1n[nf] = C1v[n]; b2n[nf] = b2v[n];
  }

  // ---------- GEMM1: [64 x 384] @ [384 x 128] ----------
  f32x4 acc[4][2];
#pragma unroll
  for (int mf = 0; mf < 4; ++mf)
#pragma unroll
    for (int nf = 0; nf < 2; ++nf)
      acc[mf][nf] = (f32x4){0.f, 0.f, 0.f, 0.f};

  short8 af[4], bfr[2];
#pragma unroll
  for (int mf = 0; mf < 4; ++mf)
    af[mf] = *(const short8*)&Abuf[mf * 16 + lr][lk];
#pragma unroll
  for (int nf = 0; nf < 2; ++nf)
    bfr[nf] = *(const short8*)&Wgt[(size_t)(n0 + nf * 16 + lr) * CAT + lk];

#pragma unroll
  for (int kk = 0; kk < CAT; kk += 32) {
    short8 an[4], bn[2];
    if (kk + 32 < CAT) {
#pragma unroll
      for (int nf = 0; nf < 2; ++nf)
        bn[nf] = *(const short8*)&Wgt[(size_t)(n0 + nf * 16 + lr) * CAT + (kk + 32) + lk];
#pragma unroll
      for (int mf = 0; mf < 4; ++mf)
        an[mf] = *(const short8*)&Abuf[mf * 16 + lr][(kk + 32) + lk];
    }
#pragma unroll
    for (int mf = 0; mf < 4; ++mf)
#pragma unroll
      for (int nf = 0; nf < 2; ++nf)
        acc[mf][nf] = __builtin_amdgcn_mfma_f32_16x16x32_bf16(af[mf], bfr[nf], acc[mf][nf], 0, 0, 0);
    if (kk + 32 < CAT) {
#pragma unroll
      for (int mf = 0; mf < 4; ++mf) af[mf] = an[mf];
#pragma unroll
      for (int nf = 0; nf < 2; ++nf) bfr[nf] = bn[nf];
    }
  }

  // epilogue 1: folded LN correction + bias + LeakyReLU -> Hbuf (bf16)
#pragma unroll
  for (int mf = 0; mf < 4; ++mf) {
#pragma unroll
    for (int nf = 0; nf < 2; ++nf) {
      const int n = n0 + nf * 16 + lr;
#pragma unroll
      for (int j = 0; j < 4; ++j) {
        const int m = mf * 16 + lkrow * 4 + j;
        float h = fmaf(rsS[m], acc[mf][nf][j] - muS[m] * Gn[nf], C1n[nf]);
        h = (h >= 0.f) ? h : 0.01f * h;
        Hbuf[m][n] = f2bf(h);
      }
    }
  }
  __syncthreads();

  // ---------- GEMM2: [64 x 128] @ [128 x 128] ----------
  f32x4 acc2[4][2];
#pragma unroll
  for (int mf = 0; mf < 4; ++mf)
#pragma unroll
    for (int nf = 0; nf < 2; ++nf)
      acc2[mf][nf] = (f32x4){0.f, 0.f, 0.f, 0.f};

#pragma unroll
  for (int kk = 0; kk < 128; kk += 32) {
    short8 a2[4], b2f[2];
#pragma unroll
    for (int mf = 0; mf < 4; ++mf)
      a2[mf] = *(const short8*)&Hbuf[mf * 16 + lr][kk + lk];
#pragma unroll
    for (int nf = 0; nf < 2; ++nf)
      b2f[nf] = *(const short8*)&W2t[(size_t)(n0 + nf * 16 + lr) * 128 + kk + lk];
#pragma unroll
    for (int mf = 0; mf < 4; ++mf)
#pragma unroll
      for (int nf = 0; nf < 2; ++nf)
        acc2[mf][nf] = __builtin_amdgcn_mfma_f32_16x16x32_bf16(a2[mf], b2f[nf], acc2[mf][nf], 0, 0, 0);
  }

  // epilogue 2: out = e + h2 + b2
  const size_t base = (size_t)blk * BM * 128;
#pragma unroll
  for (int mf = 0; mf < 4; ++mf) {
#pragma unroll
    for (int nf = 0; nf < 2; ++nf) {
      const int n = n0 + nf * 16 + lr;
#pragma unroll
      for (int j = 0; j < 4; ++j) {
        const int m = mf * 16 + lkrow * 4 + j;
        const size_t off = base + (size_t)m * 128 + n;
        out[off] = eptr[off] + acc2[mf][nf][j] + b2n[nf];
      }
    }
  }
}

extern "C" void kernel_launch(void* const* d_in, const int* in_sizes, int n_in,
                              void* d_out, int out_size, void* d_ws, size_t ws_size,
                              hipStream_t stream) {
  const float* node_feat = (const float*)d_in[0];
  const int* esrc        = (const int*)d_in[1];
  const int* edst        = (const int*)d_in[2];
  const float* e         = (const float*)d_in[3];
  const float* gamma     = (const float*)d_in[4];
  const float* beta      = (const float*)d_in[5];
  const float* W1        = (const float*)d_in[6];
  const float* b1        = (const float*)d_in[7];
  const float* W2        = (const float*)d_in[8];
  const float* b2        = (const float*)d_in[9];
  float* out = (float*)d_out;

  unsigned short* Wgt = (unsigned short*)d_ws;        // 128*384 bf16 = 98304 B
  unsigned short* W2t = Wgt + 128 * 384;              // 128*128 bf16 = 32768 B
  float* G  = (float*)(W2t + 128 * 128);              // 512 B
  float* C1 = G + 128;                                // 512 B

  prep_w<<<192, 256, 0, stream>>>(W1, gamma, W2, Wgt, W2t);
  prep_gc<<<1, 128, 0, stream>>>(W1, gamma, beta, b1, G, C1);

  edge_fused<<<NEDGES / BM, 256, 0, stream>>>(node_feat, esrc, edst, e,
                                              Wgt, W2t, G, C1, b2, out);
}

// Round 2
// 368.926 us; speedup vs baseline: 1.0949x; 1.0949x over previous
//
#include <hip/hip_runtime.h>
#include <hip/hip_bf16.h>

typedef __attribute__((ext_vector_type(8))) short short8;
typedef __attribute__((ext_vector_type(4))) float f32x4;

#define NEDGES 800000
#define BM 64
#define CAT 384
#define APAD 8

__device__ __forceinline__ unsigned short f2bf(float f) {
  union { float f; unsigned u; } v; v.f = f;
  unsigned r = v.u + 0x7fffu + ((v.u >> 16) & 1u);
  return (unsigned short)(r >> 16);
}

__device__ __forceinline__ float bf2f(unsigned short u) {
  union { unsigned u; float f; } v; v.u = ((unsigned)u) << 16;
  return v.f;
}

// ---------------- prep kernels ----------------

__global__ void prep_w(const float* __restrict__ W1, const float* __restrict__ gamma,
                       const float* __restrict__ W2,
                       unsigned short* __restrict__ Wgt, unsigned short* __restrict__ W2t) {
  int idx = blockIdx.x * 256 + threadIdx.x;
  if (idx < 128 * 384) {
    int n = idx / 384, k = idx % 384;
    Wgt[idx] = f2bf(gamma[k] * W1[k * 128 + n]);
  }
  if (idx < 128 * 128) {
    int n = idx / 128, k = idx % 128;
    W2t[idx] = f2bf(W2[k * 128 + n]);
  }
}

__global__ void prep_gc(const float* __restrict__ W1, const float* __restrict__ gamma,
                        const float* __restrict__ beta, const float* __restrict__ b1,
                        float* __restrict__ G, float* __restrict__ C1) {
  int n = threadIdx.x;  // 128 threads
  float g = 0.f, b = 0.f;
  for (int k = 0; k < 384; ++k) {
    float w = W1[k * 128 + n];
    g = fmaf(gamma[k], w, g);
    b = fmaf(beta[k], w, b);
  }
  G[n] = g;
  C1[n] = b + b1[n];
}

// ---------------- fused main kernel ----------------
// LDS: single Abuf [64][392] bf16 (50 KB) -> 3 blocks/CU.
//   cols 0..255: x_i | x_j  (consumed by GEMM1; cols 0..127 then reused as Hbuf)
//   cols 256..383: e        (consumed by GEMM1 AND the residual epilogue)
__global__ __launch_bounds__(256, 3) void edge_fused(
    const float* __restrict__ node_feat,
    const int* __restrict__ esrc,
    const int* __restrict__ edst,
    const float* __restrict__ eptr,
    const unsigned short* __restrict__ Wgt,
    const unsigned short* __restrict__ W2t,
    const float* __restrict__ Gv,
    const float* __restrict__ C1v,
    const float* __restrict__ b2v,
    float* __restrict__ out) {
  __shared__ unsigned short Abuf[BM][CAT + APAD];
  __shared__ float muS[BM];
  __shared__ float rsS[BM];

  const int tid = threadIdx.x;
  const int blk = blockIdx.x;

  // ---------- Phase 1: gather + stats + bf16 staging ----------
  {
    const int r = tid >> 2;   // edge row (0..63)
    const int t = tid & 3;    // 4 threads per row
    const size_t gid = (size_t)blk * BM + r;
    const int si = esrc[gid];
    const int di = edst[gid];
    const float4* __restrict__ p0 = (const float4*)(node_feat + (size_t)si * 128);
    const float4* __restrict__ p1 = (const float4*)(node_feat + (size_t)di * 128);
    const float4* __restrict__ p2 = (const float4*)(eptr + gid * 128);
    float sum = 0.f, sq = 0.f;
#pragma unroll
    for (int s = 0; s < 3; ++s) {
      const float4* __restrict__ p = (s == 0) ? p0 : (s == 1) ? p1 : p2;
#pragma unroll
      for (int i = 0; i < 8; ++i) {
        float4 v = p[t + 4 * i];
        sum += (v.x + v.y) + (v.z + v.w);
        sq = fmaf(v.x, v.x, sq); sq = fmaf(v.y, v.y, sq);
        sq = fmaf(v.z, v.z, sq); sq = fmaf(v.w, v.w, sq);
        ushort4 pk;
        pk.x = f2bf(v.x); pk.y = f2bf(v.y); pk.z = f2bf(v.z); pk.w = f2bf(v.w);
        *(ushort4*)&Abuf[r][s * 128 + (t + 4 * i) * 4] = pk;
      }
    }
    sum += __shfl_xor(sum, 1); sum += __shfl_xor(sum, 2);
    sq  += __shfl_xor(sq, 1);  sq  += __shfl_xor(sq, 2);
    const float mu = sum * (1.f / 384.f);
    const float var = fmaf(-mu, mu, sq * (1.f / 384.f));
    const float rstd = rsqrtf(var + 1e-5f);
    if (t == 0) { muS[r] = mu; rsS[r] = rstd; }
  }

  const int l = tid & 63;
  const int w = tid >> 6;        // wave 0..3 owns n-cols [32w, 32w+32)
  const int lr = l & 15;
  const int lkrow = l >> 4;
  const int lk = lkrow * 8;
  const int n0 = w * 32;

  // Issue these global (L2-resident) loads before the barrier so their
  // latency overlaps phase-1 tails of other waves.
  float Gn[2], C1n[2], b2n[2];
  short8 bfr[2];
#pragma unroll
  for (int nf = 0; nf < 2; ++nf) {
    const int n = n0 + nf * 16 + lr;
    Gn[nf] = Gv[n]; C1n[nf] = C1v[n]; b2n[nf] = b2v[n];
    bfr[nf] = *(const short8*)&Wgt[(size_t)n * CAT + lk];
  }

  __syncthreads();

  // ---------- GEMM1: [64 x 384] @ [384 x 128] ----------
  f32x4 acc[4][2];
#pragma unroll
  for (int mf = 0; mf < 4; ++mf)
#pragma unroll
    for (int nf = 0; nf < 2; ++nf)
      acc[mf][nf] = (f32x4){0.f, 0.f, 0.f, 0.f};

  short8 af[4];
#pragma unroll
  for (int mf = 0; mf < 4; ++mf)
    af[mf] = *(const short8*)&Abuf[mf * 16 + lr][lk];

#pragma unroll
  for (int kk = 0; kk < CAT; kk += 32) {
    short8 an[4], bn[2];
    if (kk + 32 < CAT) {
#pragma unroll
      for (int nf = 0; nf < 2; ++nf)
        bn[nf] = *(const short8*)&Wgt[(size_t)(n0 + nf * 16 + lr) * CAT + (kk + 32) + lk];
#pragma unroll
      for (int mf = 0; mf < 4; ++mf)
        an[mf] = *(const short8*)&Abuf[mf * 16 + lr][(kk + 32) + lk];
    }
#pragma unroll
    for (int mf = 0; mf < 4; ++mf)
#pragma unroll
      for (int nf = 0; nf < 2; ++nf)
        acc[mf][nf] = __builtin_amdgcn_mfma_f32_16x16x32_bf16(af[mf], bfr[nf], acc[mf][nf], 0, 0, 0);
    if (kk + 32 < CAT) {
#pragma unroll
      for (int mf = 0; mf < 4; ++mf) af[mf] = an[mf];
#pragma unroll
      for (int nf = 0; nf < 2; ++nf) bfr[nf] = bn[nf];
    }
  }

  // All waves must be done READING Abuf's x-section before we overwrite it.
  __syncthreads();

  // epilogue 1: folded LN + bias + LeakyReLU -> Hbuf aliased on Abuf[:,0..127]
#pragma unroll
  for (int mf = 0; mf < 4; ++mf) {
#pragma unroll
    for (int nf = 0; nf < 2; ++nf) {
      const int n = n0 + nf * 16 + lr;
#pragma unroll
      for (int j = 0; j < 4; ++j) {
        const int m = mf * 16 + lkrow * 4 + j;
        float h = fmaf(rsS[m], acc[mf][nf][j] - muS[m] * Gn[nf], C1n[nf]);
        h = (h >= 0.f) ? h : 0.01f * h;
        Abuf[m][n] = f2bf(h);
      }
    }
  }
  __syncthreads();

  // ---------- GEMM2: [64 x 128] @ [128 x 128] ----------
  f32x4 acc2[4][2];
#pragma unroll
  for (int mf = 0; mf < 4; ++mf)
#pragma unroll
    for (int nf = 0; nf < 2; ++nf)
      acc2[mf][nf] = (f32x4){0.f, 0.f, 0.f, 0.f};

#pragma unroll
  for (int kk = 0; kk < 128; kk += 32) {
    short8 a2[4], b2f[2];
#pragma unroll
    for (int mf = 0; mf < 4; ++mf)
      a2[mf] = *(const short8*)&Abuf[mf * 16 + lr][kk + lk];
#pragma unroll
    for (int nf = 0; nf < 2; ++nf)
      b2f[nf] = *(const short8*)&W2t[(size_t)(n0 + nf * 16 + lr) * 128 + kk + lk];
#pragma unroll
    for (int mf = 0; mf < 4; ++mf)
#pragma unroll
      for (int nf = 0; nf < 2; ++nf)
        acc2[mf][nf] = __builtin_amdgcn_mfma_f32_16x16x32_bf16(a2[mf], b2f[nf], acc2[mf][nf], 0, 0, 0);
  }

  // epilogue 2: out = e(bf16, from LDS) + h2 + b2
  const size_t base = (size_t)blk * BM * 128;
#pragma unroll
  for (int mf = 0; mf < 4; ++mf) {
#pragma unroll
    for (int nf = 0; nf < 2; ++nf) {
      const int n = n0 + nf * 16 + lr;
#pragma unroll
      for (int j = 0; j < 4; ++j) {
        const int m = mf * 16 + lkrow * 4 + j;
        const size_t off = base + (size_t)m * 128 + n;
        out[off] = bf2f(Abuf[m][256 + n]) + acc2[mf][nf][j] + b2n[nf];
      }
    }
  }
}

extern "C" void kernel_launch(void* const* d_in, const int* in_sizes, int n_in,
                              void* d_out, int out_size, void* d_ws, size_t ws_size,
                              hipStream_t stream) {
  const float* node_feat = (const float*)d_in[0];
  const int* esrc        = (const int*)d_in[1];
  const int* edst        = (const int*)d_in[2];
  const float* e         = (const float*)d_in[3];
  const float* gamma     = (const float*)d_in[4];
  const float* beta      = (const float*)d_in[5];
  const float* W1        = (const float*)d_in[6];
  const float* b1        = (const float*)d_in[7];
  const float* W2        = (const float*)d_in[8];
  const float* b2        = (const float*)d_in[9];
  float* out = (float*)d_out;

  unsigned short* Wgt = (unsigned short*)d_ws;        // 128*384 bf16
  unsigned short* W2t = Wgt + 128 * 384;              // 128*128 bf16
  float* G  = (float*)(W2t + 128 * 128);
  float* C1 = G + 128;

  prep_w<<<192, 256, 0, stream>>>(W1, gamma, W2, Wgt, W2t);
  prep_gc<<<1, 128, 0, stream>>>(W1, gamma, beta, b1, G, C1);

  edge_fused<<<NEDGES / BM, 256, 0, stream>>>(node_feat, esrc, edst, e,
                                              Wgt, W2t, G, C1, b2, out);
}